// Round 19
// baseline (1314.067 us; speedup 1.0000x reference)
//
#include <hip/hip_runtime.h>
#include <cstdint>
#include <cstddef>

#define NROWS 12288
#define FDIM 768
#define HDIM 512
#define ODIM 256
#define TOPK 31                // knn_k + 1
#define CAP 1536               // candidate buffer bound (E[C] ~ 33)

typedef float v4f __attribute__((ext_vector_type(4)));

__device__ __forceinline__ void nt_store4(float* p, float x, float y,
                                          float z, float w)
{
  v4f v; v.x = x; v.y = y; v.z = z; v.w = w;
  __builtin_nontemporal_store(v, (v4f*)p);
}

__device__ __forceinline__ float4 nt_load4(const float* p)
{
  v4f v = __builtin_nontemporal_load((const v4f*)p);
  float4 f; f.x = v.x; f.y = v.y; f.z = v.z; f.w = v.w;
  return f;
}

// ---------------------------------------------------------------------------
// 128-tile fp32 GEMM, 8x8 micro (split cols tx*4 / 64+tx*4), swizzled LDS,
// OpenBLAS-bitwise fold at K/2. Round-16 staging (VGPR 76 -> 16 waves/CU;
// register prefetch regressed to VGPR 156 / half occupancy — r17).
// Used for all three MLP layers.
// ---------------------------------------------------------------------------
template<bool RELU>
__global__ __launch_bounds__(256)
void gemm_big_nt(const float* __restrict__ A, const float* __restrict__ B,
                 const float* __restrict__ bias, float* __restrict__ C,
                 int Nout, int K)
{
  __shared__ float As[32][132];
  __shared__ float Bs[32][132];
  const int tid = threadIdx.x;
  const int tx = tid & 15, ty = tid >> 4;
  const int r0 = blockIdx.y * 128, c0 = blockIdx.x * 128;
  float acc[8][8] = {};
  float accC[8][8];
  bool first = true;
  const int Khalf = K / 2;

  for (int k0 = 0; k0 < K; k0 += 32) {
#pragma unroll
    for (int l = 0; l < 4; ++l) {
      const int lin = l * 256 + tid;
      const int row = lin >> 3, q = lin & 7;
      const float4 a = *(const float4*)(A + (size_t)(r0 + row) * K + k0 + q * 4);
      As[q + 0][row] = a.x; As[q + 8][row] = a.y;
      As[q + 16][row] = a.z; As[q + 24][row] = a.w;
      const float4 b = *(const float4*)(B + (size_t)(c0 + row) * K + k0 + q * 4);
      Bs[q + 0][row] = b.x; Bs[q + 8][row] = b.y;
      Bs[q + 16][row] = b.z; Bs[q + 24][row] = b.w;
    }
    __syncthreads();
#pragma unroll
    for (int kk = 0; kk < 32; ++kk) {
      const int kp = ((kk & 3) << 3) | (kk >> 2);
      float a8[8], b8[8];
      *(float4*)&a8[0] = *(const float4*)&As[kp][ty * 8];
      *(float4*)&a8[4] = *(const float4*)&As[kp][ty * 8 + 4];
      *(float4*)&b8[0] = *(const float4*)&Bs[kp][tx * 4];
      *(float4*)&b8[4] = *(const float4*)&Bs[kp][64 + tx * 4];
#pragma unroll
      for (int i = 0; i < 8; ++i)
#pragma unroll
        for (int j = 0; j < 8; ++j)
          acc[i][j] = fmaf(a8[i], b8[j], acc[i][j]);
    }
    __syncthreads();

    if ((k0 + 32 == Khalf) || (k0 + 32 == K)) {
#pragma unroll
      for (int i = 0; i < 8; ++i)
#pragma unroll
        for (int j = 0; j < 8; ++j) {
          accC[i][j] = first ? acc[i][j] : __fadd_rn(accC[i][j], acc[i][j]);
          acc[i][j] = 0.f;
        }
      first = false;
    }
  }

  const float4 bq0 = *(const float4*)(bias + c0 + tx * 4);
  const float4 bq1 = *(const float4*)(bias + c0 + 64 + tx * 4);
  const float bb[8] = {bq0.x, bq0.y, bq0.z, bq0.w, bq1.x, bq1.y, bq1.z, bq1.w};
#pragma unroll
  for (int i = 0; i < 8; ++i) {
    float v[8];
#pragma unroll
    for (int j = 0; j < 8; ++j) {
      v[j] = __fadd_rn(accC[i][j], bb[j]);
      if (RELU) v[j] = fmaxf(v[j], 0.f);
    }
    float* dst = C + (size_t)(r0 + ty * 8 + i) * Nout + c0;
    float4 o0; o0.x = v[0]; o0.y = v[1]; o0.z = v[2]; o0.w = v[3];
    float4 o1; o1.x = v[4]; o1.y = v[5]; o1.z = v[6]; o1.w = v[7];
    *(float4*)(dst + tx * 4) = o0;
    *(float4*)(dst + 64 + tx * 4) = o1;
  }
}

// ---------------------------------------------------------------------------
// Row L2-normalize replicating numpy pairwise_sum bitwise (n=256) + IEEE
// sqrt/divide. One thread per row.
// ---------------------------------------------------------------------------
__global__ __launch_bounds__(64)
void l2norm_np(float* __restrict__ X)
{
  const int row = blockIdx.x * 64 + threadIdx.x;
  float* x = X + (size_t)row * ODIM;

  float S = 0.f;
#pragma unroll
  for (int h = 0; h < 2; ++h) {
    const float* a = x + h * 128;
    float r0 = __fmul_rn(a[0], a[0]);
    float r1 = __fmul_rn(a[1], a[1]);
    float r2 = __fmul_rn(a[2], a[2]);
    float r3 = __fmul_rn(a[3], a[3]);
    float r4 = __fmul_rn(a[4], a[4]);
    float r5 = __fmul_rn(a[5], a[5]);
    float r6 = __fmul_rn(a[6], a[6]);
    float r7 = __fmul_rn(a[7], a[7]);
    for (int i = 8; i < 128; i += 8) {
      r0 = __fadd_rn(r0, __fmul_rn(a[i + 0], a[i + 0]));
      r1 = __fadd_rn(r1, __fmul_rn(a[i + 1], a[i + 1]));
      r2 = __fadd_rn(r2, __fmul_rn(a[i + 2], a[i + 2]));
      r3 = __fadd_rn(r3, __fmul_rn(a[i + 3], a[i + 3]));
      r4 = __fadd_rn(r4, __fmul_rn(a[i + 4], a[i + 4]));
      r5 = __fadd_rn(r5, __fmul_rn(a[i + 5], a[i + 5]));
      r6 = __fadd_rn(r6, __fmul_rn(a[i + 6], a[i + 6]));
      r7 = __fadd_rn(r7, __fmul_rn(a[i + 7], a[i + 7]));
    }
    const float half = __fadd_rn(
        __fadd_rn(__fadd_rn(r0, r1), __fadd_rn(r2, r3)),
        __fadd_rn(__fadd_rn(r4, r5), __fadd_rn(r6, r7)));
    S = (h == 0) ? half : __fadd_rn(S, half);
  }

  const float d = fmaxf(__fsqrt_rn(S), 1e-12f);
  for (int k = 0; k < ODIM; ++k) x[k] = __fdiv_rn(x[k], d);
}

// ---------------------------------------------------------------------------
// SYMMETRIC fp32 sim GEMM: S = E @ E^T, wrap-mapped triangular grid (49 x 96
// = 4704 blocks covering the 4656 upper-triangle tiles; 48 duplicates write
// bit-identical bytes — benign). Round-16 staging (VGPR 76, 16 waves/CU).
// S stores are NON-TEMPORAL (no L2 allocate) so the 604 MB stream doesn't
// evict the 12.6 MB E panels (r18 FETCH was 8.5x E size = L2 thrash).
// Off-diag tiles mirrored directly from registers.
// fmaf(a,b,c)==fmaf(b,a,c) -> mirrored chain bit-identical.
// ---------------------------------------------------------------------------
__global__ __launch_bounds__(256)
void sim_gemm_sym(const float* __restrict__ E, float* __restrict__ S)
{
  __shared__ float As[32][132];
  __shared__ float Bs[32][132];
  const int tid = threadIdx.x;
  const int a0 = blockIdx.y;
  int b0 = a0 + blockIdx.x;
  if (b0 >= NROWS / 128) b0 -= NROWS / 128;
  const int by = min(a0, b0), bx = max(a0, b0);
  const int tx = tid & 15, ty = tid >> 4;
  const int r0 = by * 128, c0 = bx * 128;
  float acc[8][8] = {};

#pragma unroll
  for (int k0 = 0; k0 < ODIM; k0 += 32) {
#pragma unroll
    for (int l = 0; l < 4; ++l) {
      const int lin = l * 256 + tid;
      const int row = lin >> 3, q = lin & 7;
      const float4 a = *(const float4*)(E + (size_t)(r0 + row) * ODIM + k0 + q * 4);
      As[q + 0][row] = a.x; As[q + 8][row] = a.y;
      As[q + 16][row] = a.z; As[q + 24][row] = a.w;
      const float4 b = *(const float4*)(E + (size_t)(c0 + row) * ODIM + k0 + q * 4);
      Bs[q + 0][row] = b.x; Bs[q + 8][row] = b.y;
      Bs[q + 16][row] = b.z; Bs[q + 24][row] = b.w;
    }
    __syncthreads();
#pragma unroll
    for (int kk = 0; kk < 32; ++kk) {
      const int kp = ((kk & 3) << 3) | (kk >> 2);
      float a8[8], b8[8];
      *(float4*)&a8[0] = *(const float4*)&As[kp][ty * 8];
      *(float4*)&a8[4] = *(const float4*)&As[kp][ty * 8 + 4];
      *(float4*)&b8[0] = *(const float4*)&Bs[kp][tx * 4];
      *(float4*)&b8[4] = *(const float4*)&Bs[kp][64 + tx * 4];
#pragma unroll
      for (int i = 0; i < 8; ++i)
#pragma unroll
        for (int j = 0; j < 8; ++j)
          acc[i][j] = fmaf(a8[i], b8[j], acc[i][j]);
    }
    __syncthreads();
  }

  // direct tile write (rows r0.., cols c0..) — non-temporal
#pragma unroll
  for (int i = 0; i < 8; ++i) {
    float* dst = S + (size_t)(r0 + ty * 8 + i) * NROWS + c0;
    nt_store4(dst + tx * 4, acc[i][0], acc[i][1], acc[i][2], acc[i][3]);
    nt_store4(dst + 64 + tx * 4, acc[i][4], acc[i][5], acc[i][6], acc[i][7]);
  }

  if (bx == by) return;

  // mirrored tile write (rows c0.., cols r0..) straight from registers — NT
#pragma unroll
  for (int h = 0; h < 2; ++h)
#pragma unroll
    for (int j = 0; j < 4; ++j) {
      const int col = c0 + h * 64 + tx * 4 + j;
      float* dst = S + (size_t)col * NROWS + r0 + ty * 8;
      nt_store4(dst, acc[0][h * 4 + j], acc[1][h * 4 + j],
                acc[2][h * 4 + j], acc[3][h * 4 + j]);
      nt_store4(dst + 4, acc[4][h * 4 + j], acc[5][h * 4 + j],
                acc[6][h * 4 + j], acc[7][h * 4 + j]);
    }
}

// ---------------------------------------------------------------------------
// Per-row exact top-31 via THRESHOLD + COMPACTION (round-16 proven version)
// with non-temporal streaming of the S row (never re-read after this kernel).
// ---------------------------------------------------------------------------
__device__ __forceinline__ uint32_t tokey(float f)
{
  const uint32_t u = __float_as_uint(f);
  return (u & 0x80000000u) ? ~u : (u | 0x80000000u);
}

__device__ __forceinline__ float relu_fromkey(uint32_t k)
{
  return (k > 0x80000000u) ? __uint_as_float(k & 0x7FFFFFFFu) : 0.f;
}

__device__ __forceinline__ uint64_t packkc(uint32_t key, uint32_t col)
{
  return ((uint64_t)key << 32) | (0xFFFFFFFFu - col);
}

__global__ __launch_bounds__(256)
void topk_mask(float* __restrict__ S)
{
  __shared__ uint64_t c0s[256];
  __shared__ uint64_t cand[CAP];
  __shared__ uint64_t wlist[TOPK];
  __shared__ uint64_t Lsh;
  __shared__ int cnt_sh, pos_sh;

  const int tid = threadIdx.x;
  const int row = blockIdx.x;
  float* Srow = S + (size_t)row * NROWS;

  // 1. load + convert (keys stay in VGPRs), per-thread max
  uint4 kq[12];
  uint64_t c0 = 0;
#pragma unroll
  for (int i = 0; i < 12; ++i) {
    const float4 f = nt_load4(Srow + tid * 4 + i * 1024);
    const uint32_t cb = tid * 4 + i * 1024;
    uint4 k;
    k.x = tokey(f.x); k.y = tokey(f.y); k.z = tokey(f.z); k.w = tokey(f.w);
    kq[i] = k;
    uint64_t p;
    p = packkc(k.x, cb + 0); if (p > c0) c0 = p;
    p = packkc(k.y, cb + 1); if (p > c0) c0 = p;
    p = packkc(k.z, cb + 2); if (p > c0) c0 = p;
    p = packkc(k.w, cb + 3); if (p > c0) c0 = p;
  }
  c0s[tid] = c0;
  if (tid == 0) cnt_sh = 0;
  __syncthreads();

  // 2. L = 31st largest of the 256 maxima (ranks unique)
  int rank = 0;
  for (int j = 0; j < 256; ++j) rank += (c0s[j] > c0) ? 1 : 0;
  if (rank == TOPK - 1) Lsh = c0;
  __syncthreads();
  uint64_t L = Lsh;

  // 3a. count candidates
  int my = 0;
#pragma unroll
  for (int i = 0; i < 12; ++i) {
    const uint32_t cb = tid * 4 + i * 1024;
    my += (packkc(kq[i].x, cb + 0) >= L) ? 1 : 0;
    my += (packkc(kq[i].y, cb + 1) >= L) ? 1 : 0;
    my += (packkc(kq[i].z, cb + 2) >= L) ? 1 : 0;
    my += (packkc(kq[i].w, cb + 3) >= L) ? 1 : 0;
  }
  atomicAdd(&cnt_sh, my);
  __syncthreads();
  int C = cnt_sh;

  // 3b. fallback (essentially never runs; exactness preserved)
  uint64_t hi = 0xFFFFFFFFFFFFFFFFull;
  while (C > CAP) {
    const uint64_t mid = L + ((hi - L) >> 1);
    if (tid == 0) cnt_sh = 0;
    __syncthreads();
    int m2 = 0;
#pragma unroll
    for (int i = 0; i < 12; ++i) {
      const uint32_t cb = tid * 4 + i * 1024;
      m2 += (packkc(kq[i].x, cb + 0) >= mid) ? 1 : 0;
      m2 += (packkc(kq[i].y, cb + 1) >= mid) ? 1 : 0;
      m2 += (packkc(kq[i].z, cb + 2) >= mid) ? 1 : 0;
      m2 += (packkc(kq[i].w, cb + 3) >= mid) ? 1 : 0;
    }
    atomicAdd(&cnt_sh, m2);
    __syncthreads();
    const int c2 = cnt_sh;
    if (c2 >= TOPK) { L = mid; C = c2; my = m2; } else { hi = mid; }
    __syncthreads();
  }

  // 3c. compact candidates into LDS
  if (tid == 0) pos_sh = 0;
  __syncthreads();
  int base = (my > 0) ? atomicAdd(&pos_sh, my) : 0;
#pragma unroll
  for (int i = 0; i < 12; ++i) {
    const uint32_t cb = tid * 4 + i * 1024;
    uint64_t p;
    p = packkc(kq[i].x, cb + 0); if (p >= L) cand[base++] = p;
    p = packkc(kq[i].y, cb + 1); if (p >= L) cand[base++] = p;
    p = packkc(kq[i].z, cb + 2); if (p >= L) cand[base++] = p;
    p = packkc(kq[i].w, cb + 3); if (p >= L) cand[base++] = p;
  }
  __syncthreads();

  // 4. exact rank-select (ranks unique -> direct wlist placement)
  for (int idx = tid; idx < C; idx += 256) {
    const uint64_t p = cand[idx];
    int r = 0;
    for (int j = 0; j < C; ++j) r += (cand[j] > p) ? 1 : 0;
    if (r < TOPK) wlist[r] = p;
  }

  // 5. zero own columns (non-temporal), then scatter winners
#pragma unroll
  for (int i = 0; i < 12; ++i)
    nt_store4(Srow + tid * 4 + i * 1024, 0.f, 0.f, 0.f, 0.f);
  __syncthreads();
  if (tid < TOPK) {
    const uint64_t p = wlist[tid];
    const uint32_t col = 0xFFFFFFFFu - (uint32_t)p;
    Srow[col] = relu_fromkey((uint32_t)(p >> 32));
  }
}

// ---------------------------------------------------------------------------
extern "C" void kernel_launch(void* const* d_in, const int* in_sizes, int n_in,
                              void* d_out, int out_size, void* d_ws, size_t ws_size,
                              hipStream_t stream)
{
  const float* feat = (const float*)d_in[0];
  const float* W1 = (const float*)d_in[1];
  const float* b1 = (const float*)d_in[2];
  const float* W2 = (const float*)d_in[3];
  const float* b2 = (const float*)d_in[4];
  const float* W3 = (const float*)d_in[5];
  const float* b3 = (const float*)d_in[6];
  float* S = (float*)d_out;   // full sim matrix in d_out, masked in place

  // d_ws (62.9 MB): X1, X2, E
  float* X1 = (float*)d_ws;                          // 25.2 MB
  float* X2 = X1 + (size_t)NROWS * HDIM;             // 25.2 MB
  float* E  = X2 + (size_t)NROWS * HDIM;             // 12.6 MB

  gemm_big_nt<true><<<dim3(HDIM / 128, NROWS / 128), 256, 0, stream>>>(
      feat, W1, b1, X1, HDIM, FDIM);
  gemm_big_nt<true><<<dim3(HDIM / 128, NROWS / 128), 256, 0, stream>>>(
      X1, W2, b2, X2, HDIM, HDIM);
  gemm_big_nt<false><<<dim3(ODIM / 128, NROWS / 128), 256, 0, stream>>>(
      X2, W3, b3, E, ODIM, HDIM);
  l2norm_np<<<NROWS / 64, 64, 0, stream>>>(E);
  sim_gemm_sym<<<dim3(49, NROWS / 128), 256, 0, stream>>>(E, S);
  topk_mask<<<NROWS, 256, 0, stream>>>(S);
}

// Round 20
// 1029.905 us; speedup vs baseline: 1.2759x; 1.2759x over previous
//
#include <hip/hip_runtime.h>
#include <cstdint>
#include <cstddef>

#define NROWS 12288
#define FDIM 768
#define HDIM 512
#define ODIM 256
#define TOPK 31                // knn_k + 1
#define CAP 1536               // candidate buffer bound (E[C] ~ 33)

// ---------------------------------------------------------------------------
// 64-tile fp32 GEMM (OpenBLAS-bitwise: serial ascending-k FMA chains, fold
// at K/2), swizzled LDS k-rows (conflict-free). Used for layer 3 (small N).
// ---------------------------------------------------------------------------
template<bool RELU>
__global__ __launch_bounds__(256)
void gemm_nt_serial(const float* __restrict__ A, const float* __restrict__ B,
                    const float* __restrict__ bias, float* __restrict__ C,
                    int Nout, int K)
{
  __shared__ float As[32][68];
  __shared__ float Bs[32][68];
  const int tid = threadIdx.x;
  const int tx = tid & 15, ty = tid >> 4;
  const int r0 = blockIdx.y * 64, c0 = blockIdx.x * 64;
  float acc[4][4] = {};
  float accC[4][4];
  bool first = true;
  const int Khalf = K / 2;

  for (int k0 = 0; k0 < K; k0 += 32) {
#pragma unroll
    for (int l = 0; l < 2; ++l) {
      const int lin = l * 256 + tid;
      const int row = lin >> 3, kq = lin & 7;
      const float4 a = *(const float4*)(A + (size_t)(r0 + row) * K + k0 + kq * 4);
      As[kq + 0][row] = a.x; As[kq + 8][row] = a.y;
      As[kq + 16][row] = a.z; As[kq + 24][row] = a.w;
      const float4 b = *(const float4*)(B + (size_t)(c0 + row) * K + k0 + kq * 4);
      Bs[kq + 0][row] = b.x; Bs[kq + 8][row] = b.y;
      Bs[kq + 16][row] = b.z; Bs[kq + 24][row] = b.w;
    }
    __syncthreads();
#pragma unroll
    for (int kk = 0; kk < 32; ++kk) {
      const int kp = ((kk & 3) << 3) | (kk >> 2);
      const float4 av = *(const float4*)&As[kp][ty * 4];
      const float4 bv = *(const float4*)&Bs[kp][tx * 4];
      const float a4[4] = {av.x, av.y, av.z, av.w};
      const float b4[4] = {bv.x, bv.y, bv.z, bv.w};
#pragma unroll
      for (int i = 0; i < 4; ++i)
#pragma unroll
        for (int j = 0; j < 4; ++j)
          acc[i][j] = fmaf(a4[i], b4[j], acc[i][j]);
    }
    __syncthreads();

    if ((k0 + 32 == Khalf) || (k0 + 32 == K)) {
#pragma unroll
      for (int i = 0; i < 4; ++i)
#pragma unroll
        for (int j = 0; j < 4; ++j) {
          accC[i][j] = first ? acc[i][j] : __fadd_rn(accC[i][j], acc[i][j]);
          acc[i][j] = 0.f;
        }
      first = false;
    }
  }

  const float4 bq = *(const float4*)(bias + c0 + tx * 4);
  const float bb[4] = {bq.x, bq.y, bq.z, bq.w};
#pragma unroll
  for (int i = 0; i < 4; ++i) {
    float v[4];
#pragma unroll
    for (int j = 0; j < 4; ++j) {
      v[j] = __fadd_rn(accC[i][j], bb[j]);
      if (RELU) v[j] = fmaxf(v[j], 0.f);
    }
    float4 o; o.x = v[0]; o.y = v[1]; o.z = v[2]; o.w = v[3];
    *(float4*)(C + (size_t)(r0 + ty * 4 + i) * Nout + c0 + tx * 4) = o;
  }
}

// ---------------------------------------------------------------------------
// 128-tile fp32 GEMM, 8x8 micro (split cols tx*4 / 64+tx*4), swizzled LDS,
// OpenBLAS-bitwise fold at K/2. Round-16/18 staging (VGPR 76 -> 16 waves/CU).
// Used for layers 1 and 2.
// ---------------------------------------------------------------------------
template<bool RELU>
__global__ __launch_bounds__(256)
void gemm_big_nt(const float* __restrict__ A, const float* __restrict__ B,
                 const float* __restrict__ bias, float* __restrict__ C,
                 int Nout, int K)
{
  __shared__ float As[32][132];
  __shared__ float Bs[32][132];
  const int tid = threadIdx.x;
  const int tx = tid & 15, ty = tid >> 4;
  const int r0 = blockIdx.y * 128, c0 = blockIdx.x * 128;
  float acc[8][8] = {};
  float accC[8][8];
  bool first = true;
  const int Khalf = K / 2;

  for (int k0 = 0; k0 < K; k0 += 32) {
#pragma unroll
    for (int l = 0; l < 4; ++l) {
      const int lin = l * 256 + tid;
      const int row = lin >> 3, q = lin & 7;
      const float4 a = *(const float4*)(A + (size_t)(r0 + row) * K + k0 + q * 4);
      As[q + 0][row] = a.x; As[q + 8][row] = a.y;
      As[q + 16][row] = a.z; As[q + 24][row] = a.w;
      const float4 b = *(const float4*)(B + (size_t)(c0 + row) * K + k0 + q * 4);
      Bs[q + 0][row] = b.x; Bs[q + 8][row] = b.y;
      Bs[q + 16][row] = b.z; Bs[q + 24][row] = b.w;
    }
    __syncthreads();
#pragma unroll
    for (int kk = 0; kk < 32; ++kk) {
      const int kp = ((kk & 3) << 3) | (kk >> 2);
      float a8[8], b8[8];
      *(float4*)&a8[0] = *(const float4*)&As[kp][ty * 8];
      *(float4*)&a8[4] = *(const float4*)&As[kp][ty * 8 + 4];
      *(float4*)&b8[0] = *(const float4*)&Bs[kp][tx * 4];
      *(float4*)&b8[4] = *(const float4*)&Bs[kp][64 + tx * 4];
#pragma unroll
      for (int i = 0; i < 8; ++i)
#pragma unroll
        for (int j = 0; j < 8; ++j)
          acc[i][j] = fmaf(a8[i], b8[j], acc[i][j]);
    }
    __syncthreads();

    if ((k0 + 32 == Khalf) || (k0 + 32 == K)) {
#pragma unroll
      for (int i = 0; i < 8; ++i)
#pragma unroll
        for (int j = 0; j < 8; ++j) {
          accC[i][j] = first ? acc[i][j] : __fadd_rn(accC[i][j], acc[i][j]);
          acc[i][j] = 0.f;
        }
      first = false;
    }
  }

  const float4 bq0 = *(const float4*)(bias + c0 + tx * 4);
  const float4 bq1 = *(const float4*)(bias + c0 + 64 + tx * 4);
  const float bb[8] = {bq0.x, bq0.y, bq0.z, bq0.w, bq1.x, bq1.y, bq1.z, bq1.w};
#pragma unroll
  for (int i = 0; i < 8; ++i) {
    float v[8];
#pragma unroll
    for (int j = 0; j < 8; ++j) {
      v[j] = __fadd_rn(accC[i][j], bb[j]);
      if (RELU) v[j] = fmaxf(v[j], 0.f);
    }
    float* dst = C + (size_t)(r0 + ty * 8 + i) * Nout + c0;
    float4 o0; o0.x = v[0]; o0.y = v[1]; o0.z = v[2]; o0.w = v[3];
    float4 o1; o1.x = v[4]; o1.y = v[5]; o1.z = v[6]; o1.w = v[7];
    *(float4*)(dst + tx * 4) = o0;
    *(float4*)(dst + 64 + tx * 4) = o1;
  }
}

// ---------------------------------------------------------------------------
// Row L2-normalize replicating numpy pairwise_sum bitwise (n=256) + IEEE
// sqrt/divide. One thread per row.
// ---------------------------------------------------------------------------
__global__ __launch_bounds__(64)
void l2norm_np(float* __restrict__ X)
{
  const int row = blockIdx.x * 64 + threadIdx.x;
  float* x = X + (size_t)row * ODIM;

  float S = 0.f;
#pragma unroll
  for (int h = 0; h < 2; ++h) {
    const float* a = x + h * 128;
    float r0 = __fmul_rn(a[0], a[0]);
    float r1 = __fmul_rn(a[1], a[1]);
    float r2 = __fmul_rn(a[2], a[2]);
    float r3 = __fmul_rn(a[3], a[3]);
    float r4 = __fmul_rn(a[4], a[4]);
    float r5 = __fmul_rn(a[5], a[5]);
    float r6 = __fmul_rn(a[6], a[6]);
    float r7 = __fmul_rn(a[7], a[7]);
    for (int i = 8; i < 128; i += 8) {
      r0 = __fadd_rn(r0, __fmul_rn(a[i + 0], a[i + 0]));
      r1 = __fadd_rn(r1, __fmul_rn(a[i + 1], a[i + 1]));
      r2 = __fadd_rn(r2, __fmul_rn(a[i + 2], a[i + 2]));
      r3 = __fadd_rn(r3, __fmul_rn(a[i + 3], a[i + 3]));
      r4 = __fadd_rn(r4, __fmul_rn(a[i + 4], a[i + 4]));
      r5 = __fadd_rn(r5, __fmul_rn(a[i + 5], a[i + 5]));
      r6 = __fadd_rn(r6, __fmul_rn(a[i + 6], a[i + 6]));
      r7 = __fadd_rn(r7, __fmul_rn(a[i + 7], a[i + 7]));
    }
    const float half = __fadd_rn(
        __fadd_rn(__fadd_rn(r0, r1), __fadd_rn(r2, r3)),
        __fadd_rn(__fadd_rn(r4, r5), __fadd_rn(r6, r7)));
    S = (h == 0) ? half : __fadd_rn(S, half);
  }

  const float d = fmaxf(__fsqrt_rn(S), 1e-12f);
  for (int k = 0; k < ODIM; ++k) x[k] = __fdiv_rn(x[k], d);
}

// ---------------------------------------------------------------------------
// SYMMETRIC fp32 sim GEMM: S = E @ E^T, wrap-mapped triangular grid (49 x 96
// = 4704 blocks over 4656 upper tiles; 48 duplicates write identical bytes).
// BK=16: LDS halves to 16.9 KB -> 6 blocks/CU (was 4), +50% waves to hide
// staging latency (r18: VALUBusy 70% @ 16 waves/CU). With stride-132 rows
// the natural As[4q+j][row] write pattern is 2-way bank-aliased (free) --
// no k-permutation needed; As[m][row] = E[row][k0+m], reads use kk directly.
// Serial ascending-k chain preserved (k0 by 16, kk 0..15) -> bit-identical.
// Plain stores (NT builtin inflated VGPR 76->152 in r19 -- do not use).
// ---------------------------------------------------------------------------
__global__ __launch_bounds__(256)
void sim_gemm_sym(const float* __restrict__ E, float* __restrict__ S)
{
  __shared__ float As[16][132];
  __shared__ float Bs[16][132];
  const int tid = threadIdx.x;
  const int a0 = blockIdx.y;
  int b0 = a0 + blockIdx.x;
  if (b0 >= NROWS / 128) b0 -= NROWS / 128;
  const int by = min(a0, b0), bx = max(a0, b0);
  const int tx = tid & 15, ty = tid >> 4;
  const int r0 = by * 128, c0 = bx * 128;
  float acc[8][8] = {};

  for (int k0 = 0; k0 < ODIM; k0 += 16) {
#pragma unroll
    for (int l = 0; l < 2; ++l) {
      const int lin = l * 256 + tid;
      const int row = lin >> 2, q = lin & 3;   // row 0..127, q 0..3
      const float4 a = *(const float4*)(E + (size_t)(r0 + row) * ODIM + k0 + q * 4);
      As[q * 4 + 0][row] = a.x; As[q * 4 + 1][row] = a.y;
      As[q * 4 + 2][row] = a.z; As[q * 4 + 3][row] = a.w;
      const float4 b = *(const float4*)(E + (size_t)(c0 + row) * ODIM + k0 + q * 4);
      Bs[q * 4 + 0][row] = b.x; Bs[q * 4 + 1][row] = b.y;
      Bs[q * 4 + 2][row] = b.z; Bs[q * 4 + 3][row] = b.w;
    }
    __syncthreads();
#pragma unroll
    for (int kk = 0; kk < 16; ++kk) {        // serial ascending logical k
      float a8[8], b8[8];
      *(float4*)&a8[0] = *(const float4*)&As[kk][ty * 8];
      *(float4*)&a8[4] = *(const float4*)&As[kk][ty * 8 + 4];
      *(float4*)&b8[0] = *(const float4*)&Bs[kk][tx * 4];
      *(float4*)&b8[4] = *(const float4*)&Bs[kk][64 + tx * 4];
#pragma unroll
      for (int i = 0; i < 8; ++i)
#pragma unroll
        for (int j = 0; j < 8; ++j)
          acc[i][j] = fmaf(a8[i], b8[j], acc[i][j]);
    }
    __syncthreads();
  }

  // direct tile write (rows r0.., cols c0..)
#pragma unroll
  for (int i = 0; i < 8; ++i) {
    float4 o0, o1;
    o0.x = acc[i][0]; o0.y = acc[i][1]; o0.z = acc[i][2]; o0.w = acc[i][3];
    o1.x = acc[i][4]; o1.y = acc[i][5]; o1.z = acc[i][6]; o1.w = acc[i][7];
    float* dst = S + (size_t)(r0 + ty * 8 + i) * NROWS + c0;
    *(float4*)(dst + tx * 4) = o0;
    *(float4*)(dst + 64 + tx * 4) = o1;
  }

  if (bx == by) return;

  // mirrored tile write (rows c0.., cols r0..) straight from registers
#pragma unroll
  for (int h = 0; h < 2; ++h)
#pragma unroll
    for (int j = 0; j < 4; ++j) {
      const int col = c0 + h * 64 + tx * 4 + j;
      float4 va, vb;
      va.x = acc[0][h * 4 + j]; va.y = acc[1][h * 4 + j];
      va.z = acc[2][h * 4 + j]; va.w = acc[3][h * 4 + j];
      vb.x = acc[4][h * 4 + j]; vb.y = acc[5][h * 4 + j];
      vb.z = acc[6][h * 4 + j]; vb.w = acc[7][h * 4 + j];
      float* dst = S + (size_t)col * NROWS + r0 + ty * 8;
      *(float4*)dst = va;
      *(float4*)(dst + 4) = vb;
    }
}

// ---------------------------------------------------------------------------
// Per-row exact top-31 via THRESHOLD + COMPACTION (round-16/18 proven).
// ---------------------------------------------------------------------------
__device__ __forceinline__ uint32_t tokey(float f)
{
  const uint32_t u = __float_as_uint(f);
  return (u & 0x80000000u) ? ~u : (u | 0x80000000u);
}

__device__ __forceinline__ float relu_fromkey(uint32_t k)
{
  return (k > 0x80000000u) ? __uint_as_float(k & 0x7FFFFFFFu) : 0.f;
}

__device__ __forceinline__ uint64_t packkc(uint32_t key, uint32_t col)
{
  return ((uint64_t)key << 32) | (0xFFFFFFFFu - col);
}

__global__ __launch_bounds__(256)
void topk_mask(float* __restrict__ S)
{
  __shared__ uint64_t c0s[256];
  __shared__ uint64_t cand[CAP];
  __shared__ uint64_t wlist[TOPK];
  __shared__ uint64_t Lsh;
  __shared__ int cnt_sh, pos_sh;

  const int tid = threadIdx.x;
  const int row = blockIdx.x;
  float* Srow = S + (size_t)row * NROWS;

  // 1. load + convert (keys stay in VGPRs), per-thread max
  uint4 kq[12];
  uint64_t c0 = 0;
#pragma unroll
  for (int i = 0; i < 12; ++i) {
    const float4 f = *(const float4*)(Srow + tid * 4 + i * 1024);
    const uint32_t cb = tid * 4 + i * 1024;
    uint4 k;
    k.x = tokey(f.x); k.y = tokey(f.y); k.z = tokey(f.z); k.w = tokey(f.w);
    kq[i] = k;
    uint64_t p;
    p = packkc(k.x, cb + 0); if (p > c0) c0 = p;
    p = packkc(k.y, cb + 1); if (p > c0) c0 = p;
    p = packkc(k.z, cb + 2); if (p > c0) c0 = p;
    p = packkc(k.w, cb + 3); if (p > c0) c0 = p;
  }
  c0s[tid] = c0;
  if (tid == 0) cnt_sh = 0;
  __syncthreads();

  // 2. L = 31st largest of the 256 maxima (ranks unique)
  int rank = 0;
  for (int j = 0; j < 256; ++j) rank += (c0s[j] > c0) ? 1 : 0;
  if (rank == TOPK - 1) Lsh = c0;
  __syncthreads();
  uint64_t L = Lsh;

  // 3a. count candidates
  int my = 0;
#pragma unroll
  for (int i = 0; i < 12; ++i) {
    const uint32_t cb = tid * 4 + i * 1024;
    my += (packkc(kq[i].x, cb + 0) >= L) ? 1 : 0;
    my += (packkc(kq[i].y, cb + 1) >= L) ? 1 : 0;
    my += (packkc(kq[i].z, cb + 2) >= L) ? 1 : 0;
    my += (packkc(kq[i].w, cb + 3) >= L) ? 1 : 0;
  }
  atomicAdd(&cnt_sh, my);
  __syncthreads();
  int C = cnt_sh;

  // 3b. fallback (essentially never runs; exactness preserved)
  uint64_t hi = 0xFFFFFFFFFFFFFFFFull;
  while (C > CAP) {
    const uint64_t mid = L + ((hi - L) >> 1);
    if (tid == 0) cnt_sh = 0;
    __syncthreads();
    int m2 = 0;
#pragma unroll
    for (int i = 0; i < 12; ++i) {
      const uint32_t cb = tid * 4 + i * 1024;
      m2 += (packkc(kq[i].x, cb + 0) >= mid) ? 1 : 0;
      m2 += (packkc(kq[i].y, cb + 1) >= mid) ? 1 : 0;
      m2 += (packkc(kq[i].z, cb + 2) >= mid) ? 1 : 0;
      m2 += (packkc(kq[i].w, cb + 3) >= mid) ? 1 : 0;
    }
    atomicAdd(&cnt_sh, m2);
    __syncthreads();
    const int c2 = cnt_sh;
    if (c2 >= TOPK) { L = mid; C = c2; my = m2; } else { hi = mid; }
    __syncthreads();
  }

  // 3c. compact candidates into LDS
  if (tid == 0) pos_sh = 0;
  __syncthreads();
  int base = (my > 0) ? atomicAdd(&pos_sh, my) : 0;
#pragma unroll
  for (int i = 0; i < 12; ++i) {
    const uint32_t cb = tid * 4 + i * 1024;
    uint64_t p;
    p = packkc(kq[i].x, cb + 0); if (p >= L) cand[base++] = p;
    p = packkc(kq[i].y, cb + 1); if (p >= L) cand[base++] = p;
    p = packkc(kq[i].z, cb + 2); if (p >= L) cand[base++] = p;
    p = packkc(kq[i].w, cb + 3); if (p >= L) cand[base++] = p;
  }
  __syncthreads();

  // 4. exact rank-select (ranks unique -> direct wlist placement)
  for (int idx = tid; idx < C; idx += 256) {
    const uint64_t p = cand[idx];
    int r = 0;
    for (int j = 0; j < C; ++j) r += (cand[j] > p) ? 1 : 0;
    if (r < TOPK) wlist[r] = p;
  }

  // 5. zero own columns, then scatter winners
  const float4 z = {0.f, 0.f, 0.f, 0.f};
#pragma unroll
  for (int i = 0; i < 12; ++i)
    *(float4*)(Srow + tid * 4 + i * 1024) = z;
  __syncthreads();
  if (tid < TOPK) {
    const uint64_t p = wlist[tid];
    const uint32_t col = 0xFFFFFFFFu - (uint32_t)p;
    Srow[col] = relu_fromkey((uint32_t)(p >> 32));
  }
}

// ---------------------------------------------------------------------------
extern "C" void kernel_launch(void* const* d_in, const int* in_sizes, int n_in,
                              void* d_out, int out_size, void* d_ws, size_t ws_size,
                              hipStream_t stream)
{
  const float* feat = (const float*)d_in[0];
  const float* W1 = (const float*)d_in[1];
  const float* b1 = (const float*)d_in[2];
  const float* W2 = (const float*)d_in[3];
  const float* b2 = (const float*)d_in[4];
  const float* W3 = (const float*)d_in[5];
  const float* b3 = (const float*)d_in[6];
  float* S = (float*)d_out;   // full sim matrix in d_out, masked in place

  // d_ws (62.9 MB): X1, X2, E
  float* X1 = (float*)d_ws;                          // 25.2 MB
  float* X2 = X1 + (size_t)NROWS * HDIM;             // 25.2 MB
  float* E  = X2 + (size_t)NROWS * HDIM;             // 12.6 MB

  gemm_big_nt<true><<<dim3(HDIM / 128, NROWS / 128), 256, 0, stream>>>(
      feat, W1, b1, X1, HDIM, FDIM);
  gemm_big_nt<true><<<dim3(HDIM / 128, NROWS / 128), 256, 0, stream>>>(
      X1, W2, b2, X2, HDIM, HDIM);
  gemm_nt_serial<false><<<dim3(ODIM / 64, NROWS / 64), 256, 0, stream>>>(
      X2, W3, b3, E, ODIM, HDIM);
  l2norm_np<<<NROWS / 64, 64, 0, stream>>>(E);
  sim_gemm_sym<<<dim3(49, NROWS / 128), 256, 0, stream>>>(E, S);
  topk_mask<<<NROWS, 256, 0, stream>>>(S);
}